// Round 17
// baseline (90.445 us; speedup 1.0000x reference)
//
#include <hip/hip_runtime.h>
#include <hip/hip_bf16.h>
#include <stdint.h>

typedef __bf16 bf16_t;
typedef __bf16 bf16x4 __attribute__((ext_vector_type(4)));
typedef __bf16 bf16x8 __attribute__((ext_vector_type(8)));
typedef float f32x4 __attribute__((ext_vector_type(4)));
typedef __attribute__((address_space(3))) bf16_t* ldsp;

#define HEADS 8
#define ATTD 32
#define NBATCH 8
#define SEQ 2048
#define DIN 256
#define WDIM 256
#define MTOT (NBATCH*SEQ)          // 16384
#define HBSZ ((size_t)MTOT*WDIM)   // elems of ONE split-head tensor [64][2048][32]
// (1/sqrt(32)) * log2(e) — folded into Q during the QKV GEMM epilogue
#define SCALE_L2E 0.25503322964704155f

// raw v_exp_f32 (args always <= 0 here; sub-denormal results flush to 0)
#define EXP2R __builtin_amdgcn_exp2f

// v_cvt_pk_bf16_f32: pack two f32 into one u32 of 2 bf16 (lo=a, hi=b)
__device__ __forceinline__ uint32_t cvtpk(float a, float b) {
    uint32_t r;
    asm("v_cvt_pk_bf16_f32 %0, %1, %2" : "=v"(r) : "v"(a), "v"(b));
    return r;
}

// ---------------- GEMM: out[m,o] = X[m,:] . W[o,:] + bias[o] ----------------
// Tile 64(m) x 256(o), 4 waves: wave wv owns 64 rows x 64 cols (o=wv*64..).
// grid.x == 1 ->每 X row fetched from HBM exactly ONCE (was 2x with 128-wide
// tiles). LDS 40KB -> 4 blocks/CU. Grids: MODE0 (1,256,3), MODE1 (1,256,1).
// MODE 0: X = f32 (q/k/v via z), W = f32; out bf16 split-head
//         [(o>>5)*MTOT + m][o&31] at outbase + z*HBSZ; z==0 scaled by SCALE_L2E.
// MODE 1: X = bf16 (ATTo), W = f32 (Wo); out f32 plain [m][o]
template<int MODE>
__global__ __launch_bounds__(256) void gemm_kernel(
    const void* __restrict__ X0, const void* __restrict__ X1,
    const void* __restrict__ X2,
    const float* __restrict__ W0, const float* __restrict__ W1,
    const float* __restrict__ W2,
    const float* __restrict__ b0, const float* __restrict__ b1,
    const float* __restrict__ b2, void* __restrict__ outbase)
{
    __shared__ bf16_t As[64*64];     // 8 KB
    __shared__ bf16_t Bs[256*64];    // 32 KB

    const int tid = threadIdx.x;
    const int z   = blockIdx.z;
    const int m0  = blockIdx.y * 64;
    const void*  Xin  = (z == 0) ? X0 : (z == 1) ? X1 : X2;
    const float* Wf   = (z == 0) ? W0 : (z == 1) ? W1 : W2;
    const float* bias = (z == 0) ? b0 : (z == 1) ? b1 : b2;

    const int wv = tid >> 6, ln = tid & 63, g = ln >> 4, l15 = ln & 15;

    f32x4 acc[4][4];
#pragma unroll
    for (int i = 0; i < 4; ++i)
#pragma unroll
        for (int j = 0; j < 4; ++j) acc[i][j] = (f32x4){0.f,0.f,0.f,0.f};

    for (int kt = 0; kt < DIN/64; ++kt) {
        if (kt) __syncthreads();
        // stage A: 64 rows x 64 cols (512 chunks of 8)
#pragma unroll
        for (int iss = 0; iss < 2; ++iss) {
            int chunk = iss*256 + tid;
            int row = chunk >> 3, c8 = (chunk & 7) * 8;
            union { bf16_t h[8]; bf16x8 v; } av;
            if (MODE == 0) {
                const float* A = (const float*)Xin;
                float4 a0 = *(const float4*)(A + (size_t)(m0+row)*DIN + kt*64 + c8);
                float4 a1 = *(const float4*)(A + (size_t)(m0+row)*DIN + kt*64 + c8 + 4);
                av.h[0]=(bf16_t)a0.x; av.h[1]=(bf16_t)a0.y; av.h[2]=(bf16_t)a0.z; av.h[3]=(bf16_t)a0.w;
                av.h[4]=(bf16_t)a1.x; av.h[5]=(bf16_t)a1.y; av.h[6]=(bf16_t)a1.z; av.h[7]=(bf16_t)a1.w;
            } else {
                av.v = *(const bf16x8*)((const bf16_t*)Xin + (size_t)(m0+row)*DIN + kt*64 + c8);
            }
            *(bf16x8*)(As + chunk*8) = av.v;
        }
        // stage B (W): 256 rows x 64 cols (2048 chunks of 8)
#pragma unroll
        for (int iss = 0; iss < 8; ++iss) {
            int chunk = iss*256 + tid;
            int row = chunk >> 3, c8 = (chunk & 7) * 8;
            union { bf16_t h[8]; bf16x8 v; } bvv;
            float4 w0 = *(const float4*)(Wf + (size_t)row*DIN + kt*64 + c8);
            float4 w1 = *(const float4*)(Wf + (size_t)row*DIN + kt*64 + c8 + 4);
            bvv.h[0]=(bf16_t)w0.x; bvv.h[1]=(bf16_t)w0.y; bvv.h[2]=(bf16_t)w0.z; bvv.h[3]=(bf16_t)w0.w;
            bvv.h[4]=(bf16_t)w1.x; bvv.h[5]=(bf16_t)w1.y; bvv.h[6]=(bf16_t)w1.z; bvv.h[7]=(bf16_t)w1.w;
            *(bf16x8*)(Bs + chunk*8) = bvv.v;
        }
        __syncthreads();
#pragma unroll
        for (int kk = 0; kk < 2; ++kk) {
            bf16x8 af[4], bfr[4];
#pragma unroll
            for (int i = 0; i < 4; ++i)
                af[i] = *(const bf16x8*)(As + (i*16 + l15)*64 + kk*32 + g*8);
#pragma unroll
            for (int j = 0; j < 4; ++j)
                bfr[j] = *(const bf16x8*)(Bs + (wv*64 + j*16 + l15)*64 + kk*32 + g*8);
#pragma unroll
            for (int i = 0; i < 4; ++i)
#pragma unroll
                for (int j = 0; j < 4; ++j)
                    acc[i][j] = __builtin_amdgcn_mfma_f32_16x16x32_bf16(
                        af[i], bfr[j], acc[i][j], 0, 0, 0);
        }
    }

    // epilogue: C/D layout col = l15, row = g*4 + r
    if (MODE == 0) {
        // heads oh = wv*2 + (j>>1); offsets i*1024B + r*64B fold into stores
        const int mrow = m0 + g*4;
        bf16_t* out = (bf16_t*)outbase + (size_t)z * HBSZ;
        const float sc = (z == 0) ? SCALE_L2E : 1.0f;
#pragma unroll
        for (int j = 0; j < 4; ++j) {
            const int oh = wv*2 + (j >> 1);
            const int ol = (j & 1)*16 + l15;
            bf16_t* p = out + ((size_t)oh*MTOT + mrow)*ATTD + ol;
            const float bb = bias[(oh << 5) | ol];
#pragma unroll
            for (int i = 0; i < 4; ++i)
#pragma unroll
                for (int r = 0; r < 4; ++r)
                    p[i*16*ATTD + r*ATTD] = (bf16_t)((acc[i][j][r] + bb) * sc);
        }
    } else {
        const int mrow = m0 + g*4;
        const int ocol = wv*64 + l15;
        float* out = (float*)outbase;
        float bb[4];
#pragma unroll
        for (int j = 0; j < 4; ++j) bb[j] = bias[ocol + j*16];
#pragma unroll
        for (int i = 0; i < 4; ++i) {
            float* p = out + (size_t)(mrow + i*16)*WDIM + ocol;
#pragma unroll
            for (int j = 0; j < 4; ++j)
#pragma unroll
                for (int r = 0; r < 4; ++r)
                    p[r*WDIM + j*16] = acc[i][j][r] + bb[j];
        }
    }
}

// ---------------- flash attention (kv-split 8-wave blocks + merge) ----------
// r15 attn body verbatim; this round: XCD-aware 1-D grid swizzle (T1) so all
// 16 q-tile blocks of one bh land on the same XCD -> K/V are L2-resident
// (8 bh x 256KB = 2MB per XCD L2). id = (bhhi*16+qtx)*8 + bhlo.
// Qh/Kh/Vh: [64][2048][32] bf16 (bh=h*8+b); Q pre-scaled. ATTo: [b][n][h*32+d].
__global__ __launch_bounds__(512) void attn_kernel(
    const bf16_t* __restrict__ Qh, const bf16_t* __restrict__ Kh,
    const bf16_t* __restrict__ Vh, bf16_t* __restrict__ ATTo)
{
    __shared__ __align__(1024) bf16_t Ks[2][2][64*40];   // [grp][buf][kv][d] str40
    __shared__ __align__(1024) bf16_t Vsub[2][2][2048];  // [grp][buf] subtiled

    const int id  = blockIdx.x;
    const int qtx = (id >> 3) & 15;
    const int bh  = ((id >> 7) << 3) | (id & 7);
    const int hh = bh >> 3, bb = bh & 7;
    const int tid = threadIdx.x;
    const int wv = tid >> 6, ln = tid & 63, g = ln >> 4, l15 = ln & 15;
    const int grp = wv >> 2;          // 0: even kv tiles, 1: odd kv tiles
    const int wvi = wv & 3;           // wave within group: q rows wvi*16..+15
    const int t256 = tid & 255;       // staging id within group

    const int kr = t256 >> 2, kc = (t256 & 3) * 8;   // staging: 4 thr/row
    const int vdst = ((kr >> 2) * 2 + ((t256 & 3) >> 1)) * 64 + (kr & 3) * 16 + (t256 & 1) * 8;
    const f32x4 zero4 = {0.f,0.f,0.f,0.f};
    const size_t bhs = (size_t)bh * SEQ;

    float* scr = (float*)&Ks[0][0][0];   // merge scratch (dead K buffers)

    bf16x8 ones;
#pragma unroll
    for (int e = 0; e < 8; ++e) ones[e] = (bf16_t)1.0f;

    for (int half = 0; half < 2; ++half) {
        const int qt = half ? (31 - qtx) : qtx;
        const int n0 = qt * 64;
        const int nIter = (qt >> 1) + 1;   // lockstep iterations
        const int q = n0 + wvi*16 + l15;
        const bf16x8 qfrag = *(const bf16x8*)(Qh + (bhs + q)*ATTD + g*8);
        f32x4 o0 = zero4, o1 = zero4, lsum = zero4;
        float m = -1e30f;

        // prologue: stage this group's tile `grp` (always a valid address)
        {
            bf16x8 k0 = *(const bf16x8*)(Kh + (bhs + grp*64 + kr)*ATTD + kc);
            bf16x8 v0 = *(const bf16x8*)(Vh + (bhs + grp*64 + kr)*ATTD + kc);
            __syncthreads();   // prev half's LDS users (incl. merge reads) done
            *(bf16x8*)(&Ks[grp][0][kr*40 + kc]) = k0;
            *(bf16x8*)(&Vsub[grp][0][vdst]) = v0;
        }

        // strength-reduced prefetch pointers: tile grp+2, advance 128 rows/iter
        const bf16_t* kpref = Kh + (bhs + (grp+2)*64 + kr)*ATTD + kc;
        const bf16_t* vpref = Vh + (bhs + (grp+2)*64 + kr)*ATTD + kc;

        for (int t = 0; t < nIter; ++t) {
            const int cur = t & 1;
            const int myT = 2*t + grp;
            // branchless prefetch (reads beyond qt stay inside ws; unused)
            bf16x8 kreg = *(const bf16x8*)kpref; kpref += 128*ATTD;
            bf16x8 vreg = *(const bf16x8*)vpref; vpref += 128*ATTD;
            __syncthreads();   // buf[cur] staged for both groups

            if (myT <= qt) {
                // S = K·Q^T : lane (l15,g): q=l15, kv = c*16 + g*4 + r
                f32x4 s[4];
#pragma unroll
                for (int c = 0; c < 4; ++c) {
                    bf16x8 kf = *(const bf16x8*)(&Ks[grp][cur][(c*16 + l15)*40 + g*8]);
                    s[c] = __builtin_amdgcn_mfma_f32_16x16x32_bf16(kf, qfrag, zero4, 0, 0, 0);
                }
                if (myT == qt) {   // causal mask on diagonal tile
#pragma unroll
                    for (int c = 0; c < 4; ++c)
#pragma unroll
                        for (int r = 0; r < 4; ++r)
                            if (c*16 + g*4 + r > wvi*16 + l15) s[c][r] = -1e30f;
                }
                // row max tree + 2 cross-group shuffles
                float t0 = fmaxf(fmaxf(s[0][0], s[0][1]), s[0][2]);
                float t1 = fmaxf(fmaxf(s[0][3], s[1][0]), s[1][1]);
                float t2 = fmaxf(fmaxf(s[1][2], s[1][3]), s[2][0]);
                float t3 = fmaxf(fmaxf(s[2][1], s[2][2]), s[2][3]);
                float t4 = fmaxf(fmaxf(s[3][0], s[3][1]), s[3][2]);
                float pmax = fmaxf(fmaxf(fmaxf(t0, t1), fmaxf(t2, t3)),
                                   fmaxf(t4, s[3][3]));
                pmax = fmaxf(pmax, __shfl_xor(pmax, 16));
                pmax = fmaxf(pmax, __shfl_xor(pmax, 32));
                // defer-max THR=0 (exact skip)
                if (!__all(pmax <= m)) {
                    const float mnew = fmaxf(m, pmax);
                    const float alpha = EXP2R(m - mnew);
                    m = mnew;
                    lsum[0] *= alpha;
#pragma unroll
                    for (int r = 0; r < 4; ++r) { o0[r] *= alpha; o1[r] *= alpha; }
                }
                // P = exp2(s - m) via raw v_exp; pack via v_cvt_pk_bf16_f32
                union { uint32_t u[4]; bf16x8 v; } pb0, pb1;
                pb0.u[0] = cvtpk(EXP2R(s[0][0]-m), EXP2R(s[0][1]-m));
                pb0.u[1] = cvtpk(EXP2R(s[0][2]-m), EXP2R(s[0][3]-m));
                pb0.u[2] = cvtpk(EXP2R(s[1][0]-m), EXP2R(s[1][1]-m));
                pb0.u[3] = cvtpk(EXP2R(s[1][2]-m), EXP2R(s[1][3]-m));
                pb1.u[0] = cvtpk(EXP2R(s[2][0]-m), EXP2R(s[2][1]-m));
                pb1.u[1] = cvtpk(EXP2R(s[2][2]-m), EXP2R(s[2][3]-m));
                pb1.u[2] = cvtpk(EXP2R(s[3][0]-m), EXP2R(s[3][1]-m));
                pb1.u[3] = cvtpk(EXP2R(s[3][2]-m), EXP2R(s[3][3]-m));
                // V^T A-fragments via HW transpose read (issue right before
                // the wait: async asm outputs must not cross control flow)
                ldsp va = (ldsp)&Vsub[grp][cur][0] + g*128 + l15*4;
                bf16x4 t00, t01, t02, t03, t10, t11, t12, t13;
                asm volatile("ds_read_b64_tr_b16 %0, %1 offset:0"    : "=v"(t00) : "v"(va));
                asm volatile("ds_read_b64_tr_b16 %0, %1 offset:1024" : "=v"(t01) : "v"(va));
                asm volatile("ds_read_b64_tr_b16 %0, %1 offset:2048" : "=v"(t02) : "v"(va));
                asm volatile("ds_read_b64_tr_b16 %0, %1 offset:3072" : "=v"(t03) : "v"(va));
                asm volatile("ds_read_b64_tr_b16 %0, %1 offset:128"  : "=v"(t10) : "v"(va));
                asm volatile("ds_read_b64_tr_b16 %0, %1 offset:1152" : "=v"(t11) : "v"(va));
                asm volatile("ds_read_b64_tr_b16 %0, %1 offset:2176" : "=v"(t12) : "v"(va));
                asm volatile("ds_read_b64_tr_b16 %0, %1 offset:3200" : "=v"(t13) : "v"(va));
                asm volatile("s_waitcnt lgkmcnt(0)" ::: "memory");
                __builtin_amdgcn_sched_barrier(0);
                // O^T = V^T · P^T ; lsum via ones-MFMA
                o0 = __builtin_amdgcn_mfma_f32_16x16x32_bf16(
                    __builtin_shufflevector(t00, t01, 0,1,2,3,4,5,6,7), pb0.v, o0, 0,0,0);
                o0 = __builtin_amdgcn_mfma_f32_16x16x32_bf16(
                    __builtin_shufflevector(t02, t03, 0,1,2,3,4,5,6,7), pb1.v, o0, 0,0,0);
                o1 = __builtin_amdgcn_mfma_f32_16x16x32_bf16(
                    __builtin_shufflevector(t10, t11, 0,1,2,3,4,5,6,7), pb0.v, o1, 0,0,0);
                o1 = __builtin_amdgcn_mfma_f32_16x16x32_bf16(
                    __builtin_shufflevector(t12, t13, 0,1,2,3,4,5,6,7), pb1.v, o1, 0,0,0);
                lsum = __builtin_amdgcn_mfma_f32_16x16x32_bf16(ones, pb0.v, lsum, 0,0,0);
                lsum = __builtin_amdgcn_mfma_f32_16x16x32_bf16(ones, pb1.v, lsum, 0,0,0);
            }

            // branchless write of prefetched tile (last-iter write is dead)
            *(bf16x8*)(&Ks[grp][cur^1][kr*40 + kc]) = kreg;
            *(bf16x8*)(&Vsub[grp][cur^1][vdst]) = vreg;
        }

        // ---- merge group B into group A via LDS scratch ----
        __syncthreads();   // all tile reads done; K buffers now dead
        const int sidx = (wvi*64 + ln)*10;
        if (grp == 1) {
            scr[sidx]   = m;
            scr[sidx+1] = lsum[0];
#pragma unroll
            for (int r = 0; r < 4; ++r) { scr[sidx+2+r] = o0[r]; scr[sidx+6+r] = o1[r]; }
        }
        __syncthreads();
        if (grp == 0) {
            const float mB = scr[sidx], lB = scr[sidx+1];
            const float mM = fmaxf(m, mB);
            const float aA = EXP2R(m - mM), aB = EXP2R(mB - mM);
            const float inv = 1.f / (lsum[0]*aA + lB*aB);
            union { bf16_t h[4]; uint2 u; } w0, w1;
#pragma unroll
            for (int r = 0; r < 4; ++r) {
                w0.h[r] = (bf16_t)((o0[r]*aA + scr[sidx+2+r]*aB) * inv);
                w1.h[r] = (bf16_t)((o1[r]*aA + scr[sidx+6+r]*aB) * inv);
            }
            const size_t base = ((size_t)bb*SEQ + q)*WDIM + hh*ATTD;
            *(uint2*)(ATTo + base + g*4)      = w0.u;
            *(uint2*)(ATTo + base + 16 + g*4) = w1.u;
        }
    }
}

// ---------------- launch ----------------
extern "C" void kernel_launch(void* const* d_in, const int* in_sizes, int n_in,
                              void* d_out, int out_size, void* d_ws, size_t ws_size,
                              hipStream_t stream) {
    const float* q_in = (const float*)d_in[0];
    const float* k_in = (const float*)d_in[1];
    const float* v_in = (const float*)d_in[2];
    const float* Wq = (const float*)d_in[3];
    const float* bq = (const float*)d_in[4];
    const float* Wk = (const float*)d_in[5];
    const float* bk = (const float*)d_in[6];
    const float* Wv = (const float*)d_in[7];
    const float* bv = (const float*)d_in[8];
    const float* Wo = (const float*)d_in[9];
    const float* bo = (const float*)d_in[10];

    bf16_t* QKVh = (bf16_t*)d_ws;              // 3 * 8.4 MB
    bf16_t* ATTo = QKVh + 3*HBSZ;              // 8.4 MB

    gemm_kernel<0><<<dim3(1,256,3), 256, 0, stream>>>(
        q_in, k_in, v_in, Wq, Wk, Wv, bq, bk, bv, QKVh);
    attn_kernel<<<dim3(1024), 512, 0, stream>>>(
        QKVh, QKVh + HBSZ, QKVh + 2*HBSZ, ATTo);
    gemm_kernel<1><<<dim3(1,256,1), 256, 0, stream>>>(
        ATTo, nullptr, nullptr, Wo, nullptr, nullptr, bo, nullptr, nullptr, d_out);
}

// Round 18
// 75.572 us; speedup vs baseline: 1.1968x; 1.1968x over previous
//
#include <hip/hip_runtime.h>
#include <hip/hip_bf16.h>
#include <stdint.h>

typedef __bf16 bf16_t;
typedef __bf16 bf16x4 __attribute__((ext_vector_type(4)));
typedef __bf16 bf16x8 __attribute__((ext_vector_type(8)));
typedef float f32x4 __attribute__((ext_vector_type(4)));
typedef __attribute__((address_space(3))) bf16_t* ldsp;

#define HEADS 8
#define ATTD 32
#define NBATCH 8
#define SEQ 2048
#define DIN 256
#define WDIM 256
#define MTOT (NBATCH*SEQ)          // 16384
#define HBSZ ((size_t)MTOT*WDIM)   // elems of ONE split-head tensor [64][2048][32]
// (1/sqrt(32)) * log2(e) — folded into Q during the QKV GEMM epilogue
#define SCALE_L2E 0.25503322964704155f

// raw v_exp_f32 (args always <= 0 here; sub-denormal results flush to 0)
#define EXP2R __builtin_amdgcn_exp2f

// v_cvt_pk_bf16_f32: pack two f32 into one u32 of 2 bf16 (lo=a, hi=b)
__device__ __forceinline__ uint32_t cvtpk(float a, float b) {
    uint32_t r;
    asm("v_cvt_pk_bf16_f32 %0, %1, %2" : "=v"(r) : "v"(a), "v"(b));
    return r;
}

// ---------------- GEMM: out[m,o] = X[m,:] . W[o,:] + bias[o] ----------------
// Tile 64(m) x 128(o) (r15-proven, 6 blocks/CU). Grid (256, 2, z) with
// x = m-block (fastest), y = n-block: the two n-blocks of one (m,z) have ids
// differing by 256 = 0 mod 8 -> SAME XCD -> duplicate X-row read is an L2
// hit, not a second HBM fetch (T1 for the GEMM).
// MODE 0: X = f32 (q/k/v via z), W = f32; out bf16 split-head
//         [(o>>5)*MTOT + m][o&31] at outbase + z*HBSZ; z==0 scaled by SCALE_L2E.
// MODE 1: X = bf16 (ATTo), W = f32 (Wo); out f32 plain [m][o]
template<int MODE>
__global__ __launch_bounds__(256) void gemm_kernel(
    const void* __restrict__ X0, const void* __restrict__ X1,
    const void* __restrict__ X2,
    const float* __restrict__ W0, const float* __restrict__ W1,
    const float* __restrict__ W2,
    const float* __restrict__ b0, const float* __restrict__ b1,
    const float* __restrict__ b2, void* __restrict__ outbase)
{
    __shared__ bf16_t As[64*64];
    __shared__ bf16_t Bs[128*64];

    const int tid = threadIdx.x;
    const int z   = blockIdx.z;
    const int m0  = blockIdx.x * 64;    // x fastest -> m round-robins XCDs
    const int n0  = blockIdx.y * 128;   // both n-blocks of one m: same XCD
    const void*  Xin  = (z == 0) ? X0 : (z == 1) ? X1 : X2;
    const float* Wf   = (z == 0) ? W0 : (z == 1) ? W1 : W2;
    const float* bias = (z == 0) ? b0 : (z == 1) ? b1 : b2;

    const int wv = tid >> 6, ln = tid & 63, g = ln >> 4, l15 = ln & 15;

    f32x4 acc[4][2];
#pragma unroll
    for (int i = 0; i < 4; ++i)
#pragma unroll
        for (int j = 0; j < 2; ++j) acc[i][j] = (f32x4){0.f,0.f,0.f,0.f};

    for (int kt = 0; kt < DIN/64; ++kt) {
        if (kt) __syncthreads();
        // stage A: 64 rows x 64 cols (512 chunks of 8)
#pragma unroll
        for (int iss = 0; iss < 2; ++iss) {
            int chunk = iss*256 + tid;
            int row = chunk >> 3, c8 = (chunk & 7) * 8;
            union { bf16_t h[8]; bf16x8 v; } av;
            if (MODE == 0) {
                const float* A = (const float*)Xin;
                float4 a0 = *(const float4*)(A + (size_t)(m0+row)*DIN + kt*64 + c8);
                float4 a1 = *(const float4*)(A + (size_t)(m0+row)*DIN + kt*64 + c8 + 4);
                av.h[0]=(bf16_t)a0.x; av.h[1]=(bf16_t)a0.y; av.h[2]=(bf16_t)a0.z; av.h[3]=(bf16_t)a0.w;
                av.h[4]=(bf16_t)a1.x; av.h[5]=(bf16_t)a1.y; av.h[6]=(bf16_t)a1.z; av.h[7]=(bf16_t)a1.w;
            } else {
                av.v = *(const bf16x8*)((const bf16_t*)Xin + (size_t)(m0+row)*DIN + kt*64 + c8);
            }
            *(bf16x8*)(As + chunk*8) = av.v;
        }
        // stage B (W): 128 rows x 64 cols (1024 chunks of 8)
#pragma unroll
        for (int iss = 0; iss < 4; ++iss) {
            int chunk = iss*256 + tid;
            int row = chunk >> 3, c8 = (chunk & 7) * 8;
            union { bf16_t h[8]; bf16x8 v; } bvv;
            float4 w0 = *(const float4*)(Wf + (size_t)(n0+row)*DIN + kt*64 + c8);
            float4 w1 = *(const float4*)(Wf + (size_t)(n0+row)*DIN + kt*64 + c8 + 4);
            bvv.h[0]=(bf16_t)w0.x; bvv.h[1]=(bf16_t)w0.y; bvv.h[2]=(bf16_t)w0.z; bvv.h[3]=(bf16_t)w0.w;
            bvv.h[4]=(bf16_t)w1.x; bvv.h[5]=(bf16_t)w1.y; bvv.h[6]=(bf16_t)w1.z; bvv.h[7]=(bf16_t)w1.w;
            *(bf16x8*)(Bs + chunk*8) = bvv.v;
        }
        __syncthreads();
#pragma unroll
        for (int kk = 0; kk < 2; ++kk) {
            bf16x8 af[4], bfr[2];
#pragma unroll
            for (int i = 0; i < 4; ++i)
                af[i] = *(const bf16x8*)(As + (i*16 + l15)*64 + kk*32 + g*8);
#pragma unroll
            for (int j = 0; j < 2; ++j)
                bfr[j] = *(const bf16x8*)(Bs + (wv*32 + j*16 + l15)*64 + kk*32 + g*8);
#pragma unroll
            for (int i = 0; i < 4; ++i)
#pragma unroll
                for (int j = 0; j < 2; ++j)
                    acc[i][j] = __builtin_amdgcn_mfma_f32_16x16x32_bf16(
                        af[i], bfr[j], acc[i][j], 0, 0, 0);
        }
    }

    // epilogue: C/D layout col = l15, row = g*4 + r
    if (MODE == 0) {
        // one head per wave: oh = n0>>5 + wv; offsets i*1024B + r*64B fold in
        const int mrow = m0 + g*4;
        const int oh   = (n0 >> 5) + wv;
        bf16_t* out = (bf16_t*)outbase + (size_t)z * HBSZ;
        const float sc = (z == 0) ? SCALE_L2E : 1.0f;
#pragma unroll
        for (int j = 0; j < 2; ++j) {
            const int ol = j*16 + l15;
            bf16_t* p = out + ((size_t)oh*MTOT + mrow)*ATTD + ol;
            const float bb = bias[(oh << 5) | ol];
#pragma unroll
            for (int i = 0; i < 4; ++i)
#pragma unroll
                for (int r = 0; r < 4; ++r)
                    p[i*16*ATTD + r*ATTD] = (bf16_t)((acc[i][j][r] + bb) * sc);
        }
    } else {
        const int mrow = m0 + g*4;
        const int ocol = n0 + wv*32 + l15;
        float* out = (float*)outbase;
        float bb[2];
        bb[0] = bias[ocol]; bb[1] = bias[ocol + 16];
#pragma unroll
        for (int i = 0; i < 4; ++i) {
            float* p = out + (size_t)(mrow + i*16)*WDIM + ocol;
#pragma unroll
            for (int j = 0; j < 2; ++j)
#pragma unroll
                for (int r = 0; r < 4; ++r)
                    p[r*WDIM + j*16] = acc[i][j][r] + bb[j];
        }
    }
}

// ---------------- flash attention (kv-split 8-wave blocks + merge) ----------
// r16 verbatim: XCD-aware 1-D grid swizzle (all 16 q-tile blocks of one bh on
// one XCD -> K/V L2-resident), kv-split across wave groups, flash merge.
// Qh/Kh/Vh: [64][2048][32] bf16 (bh=h*8+b); Q pre-scaled. ATTo: [b][n][h*32+d].
__global__ __launch_bounds__(512) void attn_kernel(
    const bf16_t* __restrict__ Qh, const bf16_t* __restrict__ Kh,
    const bf16_t* __restrict__ Vh, bf16_t* __restrict__ ATTo)
{
    __shared__ __align__(1024) bf16_t Ks[2][2][64*40];   // [grp][buf][kv][d] str40
    __shared__ __align__(1024) bf16_t Vsub[2][2][2048];  // [grp][buf] subtiled

    const int id  = blockIdx.x;
    const int qtx = (id >> 3) & 15;
    const int bh  = ((id >> 7) << 3) | (id & 7);
    const int hh = bh >> 3, bb = bh & 7;
    const int tid = threadIdx.x;
    const int wv = tid >> 6, ln = tid & 63, g = ln >> 4, l15 = ln & 15;
    const int grp = wv >> 2;          // 0: even kv tiles, 1: odd kv tiles
    const int wvi = wv & 3;           // wave within group: q rows wvi*16..+15
    const int t256 = tid & 255;       // staging id within group

    const int kr = t256 >> 2, kc = (t256 & 3) * 8;   // staging: 4 thr/row
    const int vdst = ((kr >> 2) * 2 + ((t256 & 3) >> 1)) * 64 + (kr & 3) * 16 + (t256 & 1) * 8;
    const f32x4 zero4 = {0.f,0.f,0.f,0.f};
    const size_t bhs = (size_t)bh * SEQ;

    float* scr = (float*)&Ks[0][0][0];   // merge scratch (dead K buffers)

    bf16x8 ones;
#pragma unroll
    for (int e = 0; e < 8; ++e) ones[e] = (bf16_t)1.0f;

    for (int half = 0; half < 2; ++half) {
        const int qt = half ? (31 - qtx) : qtx;
        const int n0 = qt * 64;
        const int nIter = (qt >> 1) + 1;   // lockstep iterations
        const int q = n0 + wvi*16 + l15;
        const bf16x8 qfrag = *(const bf16x8*)(Qh + (bhs + q)*ATTD + g*8);
        f32x4 o0 = zero4, o1 = zero4, lsum = zero4;
        float m = -1e30f;

        // prologue: stage this group's tile `grp` (always a valid address)
        {
            bf16x8 k0 = *(const bf16x8*)(Kh + (bhs + grp*64 + kr)*ATTD + kc);
            bf16x8 v0 = *(const bf16x8*)(Vh + (bhs + grp*64 + kr)*ATTD + kc);
            __syncthreads();   // prev half's LDS users (incl. merge reads) done
            *(bf16x8*)(&Ks[grp][0][kr*40 + kc]) = k0;
            *(bf16x8*)(&Vsub[grp][0][vdst]) = v0;
        }

        // strength-reduced prefetch pointers: tile grp+2, advance 128 rows/iter
        const bf16_t* kpref = Kh + (bhs + (grp+2)*64 + kr)*ATTD + kc;
        const bf16_t* vpref = Vh + (bhs + (grp+2)*64 + kr)*ATTD + kc;

        for (int t = 0; t < nIter; ++t) {
            const int cur = t & 1;
            const int myT = 2*t + grp;
            // branchless prefetch (reads beyond qt stay inside ws; unused)
            bf16x8 kreg = *(const bf16x8*)kpref; kpref += 128*ATTD;
            bf16x8 vreg = *(const bf16x8*)vpref; vpref += 128*ATTD;
            __syncthreads();   // buf[cur] staged for both groups

            if (myT <= qt) {
                // S = K·Q^T : lane (l15,g): q=l15, kv = c*16 + g*4 + r
                f32x4 s[4];
#pragma unroll
                for (int c = 0; c < 4; ++c) {
                    bf16x8 kf = *(const bf16x8*)(&Ks[grp][cur][(c*16 + l15)*40 + g*8]);
                    s[c] = __builtin_amdgcn_mfma_f32_16x16x32_bf16(kf, qfrag, zero4, 0, 0, 0);
                }
                if (myT == qt) {   // causal mask on diagonal tile
#pragma unroll
                    for (int c = 0; c < 4; ++c)
#pragma unroll
                        for (int r = 0; r < 4; ++r)
                            if (c*16 + g*4 + r > wvi*16 + l15) s[c][r] = -1e30f;
                }
                // row max tree + 2 cross-group shuffles
                float t0 = fmaxf(fmaxf(s[0][0], s[0][1]), s[0][2]);
                float t1 = fmaxf(fmaxf(s[0][3], s[1][0]), s[1][1]);
                float t2 = fmaxf(fmaxf(s[1][2], s[1][3]), s[2][0]);
                float t3 = fmaxf(fmaxf(s[2][1], s[2][2]), s[2][3]);
                float t4 = fmaxf(fmaxf(s[3][0], s[3][1]), s[3][2]);
                float pmax = fmaxf(fmaxf(fmaxf(t0, t1), fmaxf(t2, t3)),
                                   fmaxf(t4, s[3][3]));
                pmax = fmaxf(pmax, __shfl_xor(pmax, 16));
                pmax = fmaxf(pmax, __shfl_xor(pmax, 32));
                // defer-max THR=0 (exact skip)
                if (!__all(pmax <= m)) {
                    const float mnew = fmaxf(m, pmax);
                    const float alpha = EXP2R(m - mnew);
                    m = mnew;
                    lsum[0] *= alpha;
#pragma unroll
                    for (int r = 0; r < 4; ++r) { o0[r] *= alpha; o1[r] *= alpha; }
                }
                // P = exp2(s - m) via raw v_exp; pack via v_cvt_pk_bf16_f32
                union { uint32_t u[4]; bf16x8 v; } pb0, pb1;
                pb0.u[0] = cvtpk(EXP2R(s[0][0]-m), EXP2R(s[0][1]-m));
                pb0.u[1] = cvtpk(EXP2R(s[0][2]-m), EXP2R(s[0][3]-m));
                pb0.u[2] = cvtpk(EXP2R(s[1][0]-m), EXP2R(s[1][1]-m));
                pb0.u[3] = cvtpk(EXP2R(s[1][2]-m), EXP2R(s[1][3]-m));
                pb1.u[0] = cvtpk(EXP2R(s[2][0]-m), EXP2R(s[2][1]-m));
                pb1.u[1] = cvtpk(EXP2R(s[2][2]-m), EXP2R(s[2][3]-m));
                pb1.u[2] = cvtpk(EXP2R(s[3][0]-m), EXP2R(s[3][1]-m));
                pb1.u[3] = cvtpk(EXP2R(s[3][2]-m), EXP2R(s[3][3]-m));
                // V^T A-fragments via HW transpose read (issue right before
                // the wait: async asm outputs must not cross control flow)
                ldsp va = (ldsp)&Vsub[grp][cur][0] + g*128 + l15*4;
                bf16x4 t00, t01, t02, t03, t10, t11, t12, t13;
                asm volatile("ds_read_b64_tr_b16 %0, %1 offset:0"    : "=v"(t00) : "v"(va));
                asm volatile("ds_read_b64_tr_b16 %0, %1 offset:1024" : "=v"(t01) : "v"(va));
                asm volatile("ds_read_b64_tr_b16 %0, %1 offset:2048" : "=v"(t02) : "v"(va));
                asm volatile("ds_read_b64_tr_b16 %0, %1 offset:3072" : "=v"(t03) : "v"(va));
                asm volatile("ds_read_b64_tr_b16 %0, %1 offset:128"  : "=v"(t10) : "v"(va));
                asm volatile("ds_read_b64_tr_b16 %0, %1 offset:1152" : "=v"(t11) : "v"(va));
                asm volatile("ds_read_b64_tr_b16 %0, %1 offset:2176" : "=v"(t12) : "v"(va));
                asm volatile("ds_read_b64_tr_b16 %0, %1 offset:3200" : "=v"(t13) : "v"(va));
                asm volatile("s_waitcnt lgkmcnt(0)" ::: "memory");
                __builtin_amdgcn_sched_barrier(0);
                // O^T = V^T · P^T ; lsum via ones-MFMA
                o0 = __builtin_amdgcn_mfma_f32_16x16x32_bf16(
                    __builtin_shufflevector(t00, t01, 0,1,2,3,4,5,6,7), pb0.v, o0, 0,0,0);
                o0 = __builtin_amdgcn_mfma_f32_16x16x32_bf16(
                    __builtin_shufflevector(t02, t03, 0,1,2,3,4,5,6,7), pb1.v, o0, 0,0,0);
                o1 = __builtin_amdgcn_mfma_f32_16x16x32_bf16(
                    __builtin_shufflevector(t10, t11, 0,1,2,3,4,5,6,7), pb0.v, o1, 0,0,0);
                o1 = __builtin_amdgcn_mfma_f32_16x16x32_bf16(
                    __builtin_shufflevector(t12, t13, 0,1,2,3,4,5,6,7), pb1.v, o1, 0,0,0);
                lsum = __builtin_amdgcn_mfma_f32_16x16x32_bf16(ones, pb0.v, lsum, 0,0,0);
                lsum = __builtin_amdgcn_mfma_f32_16x16x32_bf16(ones, pb1.v, lsum, 0,0,0);
            }

            // branchless write of prefetched tile (last-iter write is dead)
            *(bf16x8*)(&Ks[grp][cur^1][kr*40 + kc]) = kreg;
            *(bf16x8*)(&Vsub[grp][cur^1][vdst]) = vreg;
        }

        // ---- merge group B into group A via LDS scratch ----
        __syncthreads();   // all tile reads done; K buffers now dead
        const int sidx = (wvi*64 + ln)*10;
        if (grp == 1) {
            scr[sidx]   = m;
            scr[sidx+1] = lsum[0];
#pragma unroll
            for (int r = 0; r < 4; ++r) { scr[sidx+2+r] = o0[r]; scr[sidx+6+r] = o1[r]; }
        }
        __syncthreads();
        if (grp == 0) {
            const float mB = scr[sidx], lB = scr[sidx+1];
            const float mM = fmaxf(m, mB);
            const float aA = EXP2R(m - mM), aB = EXP2R(mB - mM);
            const float inv = 1.f / (lsum[0]*aA + lB*aB);
            union { bf16_t h[4]; uint2 u; } w0, w1;
#pragma unroll
            for (int r = 0; r < 4; ++r) {
                w0.h[r] = (bf16_t)((o0[r]*aA + scr[sidx+2+r]*aB) * inv);
                w1.h[r] = (bf16_t)((o1[r]*aA + scr[sidx+6+r]*aB) * inv);
            }
            const size_t base = ((size_t)bb*SEQ + q)*WDIM + hh*ATTD;
            *(uint2*)(ATTo + base + g*4)      = w0.u;
            *(uint2*)(ATTo + base + 16 + g*4) = w1.u;
        }
    }
}

// ---------------- launch ----------------
extern "C" void kernel_launch(void* const* d_in, const int* in_sizes, int n_in,
                              void* d_out, int out_size, void* d_ws, size_t ws_size,
                              hipStream_t stream) {
    const float* q_in = (const float*)d_in[0];
    const float* k_in = (const float*)d_in[1];
    const float* v_in = (const float*)d_in[2];
    const float* Wq = (const float*)d_in[3];
    const float* bq = (const float*)d_in[4];
    const float* Wk = (const float*)d_in[5];
    const float* bk = (const float*)d_in[6];
    const float* Wv = (const float*)d_in[7];
    const float* bv = (const float*)d_in[8];
    const float* Wo = (const float*)d_in[9];
    const float* bo = (const float*)d_in[10];

    bf16_t* QKVh = (bf16_t*)d_ws;              // 3 * 8.4 MB
    bf16_t* ATTo = QKVh + 3*HBSZ;              // 8.4 MB

    gemm_kernel<0><<<dim3(256,2,3), 256, 0, stream>>>(
        q_in, k_in, v_in, Wq, Wk, Wv, bq, bk, bv, QKVh);
    attn_kernel<<<dim3(1024), 512, 0, stream>>>(
        QKVh, QKVh + HBSZ, QKVh + 2*HBSZ, ATTo);
    gemm_kernel<1><<<dim3(256,2,1), 256, 0, stream>>>(
        ATTo, nullptr, nullptr, Wo, nullptr, nullptr, bo, nullptr, nullptr, d_out);
}